// Round 1
// 425.040 us; speedup vs baseline: 1.0472x; 1.0472x over previous
//
#include <hip/hip_runtime.h>

// Masked dual-branch ConvTranspose2d (stride 2, k3, pad 1, outpad 1), fp32 in/out.
//   out = mask ? (tconv(x, high_w)+hb) : (tconv(xr, low2_w)+lb),  xr = 1x1(x, low1_w)+l1b
// Internally: weights/x-tiles/xr downcast to bf16, mfma_f32_16x16x32_bf16, f32 accum.
// d_ws layout (u16 elems): [0, 4194304) xr (bf16) | [4194304, +36864) whi frags | +10240 wlo frags
//
// R1 change: MFMA operands swapped (weights as A, pixels as B) so D is
// [row=och(4q+reg)][col=pixel(lane&15)]. Epilogue pairs px=0/px=1 phases and
// stores float2 per lane -> 16-lane-contiguous 128B segments per och instead of
// 64 scattered 4B stores 256KB apart. Mask read as one coalesced float2/lane.

typedef unsigned short u16;
typedef unsigned int   u32;
typedef __bf16 bf16x8 __attribute__((ext_vector_type(8)));
typedef u16    u16x8  __attribute__((ext_vector_type(8)));
typedef float  f32x4  __attribute__((ext_vector_type(4)));

#define DEV static __device__ __forceinline__

DEV u16   f2bf(float f){ u32 u = __builtin_bit_cast(u32, f); u += 0x7FFF + ((u >> 16) & 1); return (u16)(u >> 16); }
DEV bf16x8 asb(u16x8 v){ return __builtin_bit_cast(bf16x8, v); }
// NOTE: first frag arg is the MFMA A operand, second is B.
#define MF(acc, A, B) acc = __builtin_amdgcn_mfma_f32_16x16x32_bf16(asb(A), asb(B), acc, 0, 0, 0)

// ---------------- kernel 0: pre-shuffle weights into MFMA B-fragment order (f32 -> bf16) ----------------
// whi[(tap*2+Q)*4 + tile][lane][e] = bf16(high_w[c=32Q+8*(lane>>4)+e][och=16*tile+(lane&15)][kh][kw])
// wlo[f][tile][lane][e]: packed 2-tap (16ch each) frags; quads 0,1 = tapA, quads 2,3 = tapB.
__global__ __launch_bounds__(256) void wprep(const float* __restrict__ hw, const float* __restrict__ lw,
                                             u16* __restrict__ whi, u16* __restrict__ wlo)
{
  int t = blockIdx.x * 256 + threadIdx.x;
  if (t < 36864) {
    int e = t & 7, lane = (t >> 3) & 63, tile = (t >> 9) & 3, Q = (t >> 11) & 1, tap = t >> 12;
    int q = lane >> 4, n = lane & 15;
    int c = 32 * Q + 8 * q + e, och = 16 * tile + n;
    whi[t] = f2bf(hw[(c * 64 + och) * 9 + tap]);
  } else if (t < 47104) {
    int t2 = t - 36864;
    int e = t2 & 7, lane = (t2 >> 3) & 63, tile = (t2 >> 9) & 3, f = t2 >> 11;
    int q = lane >> 4, n = lane & 15, och = 16 * tile + n;
    // f: {P00:(1,1)|zero, P01:(1,0)|(1,2), P10:(0,1)|(2,1), P11a:(0,0)|(0,2), P11b:(2,0)|(2,2)}
    const int ta[10] = {4, -1, 3, 5, 1, 7, 0, 2, 6, 8};
    int tap = ta[f * 2 + (q >> 1)];
    u16 v = 0;
    if (tap >= 0) { int c = 8 * (q & 1) + e; v = f2bf(lw[(c * 64 + och) * 9 + tap]); }
    wlo[t2] = v;
  }
}

// ---------------- kernel 1: xr[b][i][j][16] = bf16(low1_w (16x64) @ x + l1b) ----------------
__global__ __launch_bounds__(256) void xr_kernel(const float* __restrict__ x, const float* __restrict__ w1,
                                                 const float* __restrict__ b1, u16* __restrict__ xr)
{
  __shared__ float sw[1024];  // [c][r]
  __shared__ float sb[16];
  for (int u = threadIdx.x; u < 1024; u += 256) { int r = u & 15, c = u >> 4; sw[u] = w1[r * 64 + c]; }
  if (threadIdx.x < 16) sb[threadIdx.x] = b1[threadIdx.x];
  __syncthreads();
  int t = blockIdx.x * 256 + threadIdx.x;        // = (b*256 + i)*256 + j
  const float* xp = x + ((size_t)(t >> 16) << 22) + (t & 65535);
  float acc[16];
  #pragma unroll
  for (int r = 0; r < 16; ++r) acc[r] = sb[r];
  #pragma unroll 4
  for (int c = 0; c < 64; ++c) {
    float xv = xp[(size_t)c << 16];
    #pragma unroll
    for (int r = 0; r < 16; ++r) acc[r] = fmaf(xv, sw[c * 16 + r], acc[r]);
  }
  u32 pk[8];
  #pragma unroll
  for (int k = 0; k < 8; ++k) pk[k] = (u32)f2bf(acc[2 * k]) | ((u32)f2bf(acc[2 * k + 1]) << 16);
  uint4* dst = (uint4*)(xr + (size_t)t * 16);
  dst[0] = make_uint4(pk[0], pk[1], pk[2], pk[3]);
  dst[1] = make_uint4(pk[4], pk[5], pk[6], pk[7]);
}

// ---------------- kernel 2: 4-phase tconv + blend ----------------
// Block: (jchunk, i, b). Output rows 2i,2i+1, cols 2*j0..2*j0+127, all 64 och.
// Wave w -> och tile 16w. MFMA operands SWAPPED: D row = och(4q+reg), col = pixel(lane&15).
__global__ __launch_bounds__(256) void tconv_main(
    const float* __restrict__ x, const u16* __restrict__ xr,
    const u16* __restrict__ whi, const u16* __restrict__ wlo,
    const float* __restrict__ mask, const float* __restrict__ hbp,
    const float* __restrict__ lbp, float* __restrict__ out)
{
  __shared__ __attribute__((aligned(16))) u16 xs [2][68][72];  // [row][col][ch64 pad72] 144B col stride
  __shared__ __attribute__((aligned(16))) u16 xrs[2][68][24];  // [row][col][ch16 pad24]; ch16..23 zeroed

  const int tid  = threadIdx.x;
  const int lane = tid & 63, wid = tid >> 6;
  const int j0 = blockIdx.x * 64;
  const int i  = blockIdx.y;
  const int b  = blockIdx.z;
  const int q  = lane >> 4, n = lane & 15;

  // B-fragments in registers (coalesced 16B/lane from pre-shuffled layout)
  u16x8 bh[9][2], bl[5];
  {
    const u16x8* wh8 = (const u16x8*)whi;
    #pragma unroll
    for (int tap = 0; tap < 9; ++tap)
      #pragma unroll
      for (int Q = 0; Q < 2; ++Q)
        bh[tap][Q] = wh8[((tap * 2 + Q) * 4 + wid) * 64 + lane];
    const u16x8* wl8 = (const u16x8*)wlo;
    #pragma unroll
    for (int f = 0; f < 5; ++f) bl[f] = wl8[(f * 4 + wid) * 64 + lane];
  }
  // Per-lane biases: this lane's D rows are och = 16*wid + 4*q + reg.
  float hb4[4], lb4[4];
  #pragma unroll
  for (int r = 0; r < 4; ++r) {
    hb4[r] = hbp[16 * wid + 4 * q + r];
    lb4[r] = lbp[16 * wid + 4 * q + r];
  }

  // stage x rows {i,i+1}, cols j0..j0+63 (float2), downcast bf16, transpose to ch-contiguous
  for (int idx = tid; idx < 2 * 64 * 32; idx += 256) {
    int cp = idx & 31, c = (idx >> 5) & 63, row = idx >> 11;
    int gi = i + row, col = cp * 2;
    float2 v = make_float2(0.f, 0.f);
    if (gi < 256) v = *(const float2*)&x[((size_t)b << 22) + ((size_t)c << 16) + (gi << 8) + (j0 + col)];
    xs[row][col    ][c] = f2bf(v.x);
    xs[row][col + 1][c] = f2bf(v.y);
  }
  if (tid < 128) {  // halo col 64
    int row = tid >> 6, c = tid & 63, gi = i + row, gj = j0 + 64;
    float v = 0.f;
    if (gi < 256 && gj < 256) v = x[((size_t)b << 22) + ((size_t)c << 16) + (gi << 8) + gj];
    xs[row][64][c] = f2bf(v);
  }
  // stage xr (bf16 in ws) rows {i,i+1}, cols j0..j0+64 (contiguous dwords in global)
  for (int u = tid; u < 1040; u += 256) {
    int row = (u >= 520) ? 1 : 0;
    int uu  = u - row * 520;
    int col = uu >> 3, rcp = uu & 7;
    int gi = i + row, gj = j0 + col;
    u32 v = 0;
    if (gi < 256 && gj < 256) v = *(const u32*)(xr + ((size_t)((b * 256 + gi) * 256 + gj)) * 16 + rcp * 2);
    *(u32*)&xrs[row][col][rcp * 2] = v;
  }
  if (tid < 136) {  // zero pad channels (used as the zero half of the P00 low frag)
    int row = tid / 68, col = tid % 68;
    *(uint4*)&xrs[row][col][16] = make_uint4(0, 0, 0, 0);
  }
  __syncthreads();

  #pragma unroll
  for (int jt = 0; jt < 64; jt += 16) {
    const int colb = jt + n;   // B-frag: pixel n = lane&15
    u16x8 ah[2][2][2];         // [row][dx][Q]
    #pragma unroll
    for (int r = 0; r < 2; ++r)
      #pragma unroll
      for (int d = 0; d < 2; ++d)
        #pragma unroll
        for (int Q = 0; Q < 2; ++Q)
          ah[r][d][Q] = *(const u16x8*)&xs[r][colb + d][32 * Q + 8 * q];
    const int dq = (q < 2) ? 1 : 0;  // quads 0,1 = tapA / quads 2,3 = tapB
    u16x8 lf0 = *(const u16x8*)&xrs[0 ][colb     ][(q < 2) ? 8 * (q & 1) : 16];
    u16x8 lf1 = *(const u16x8*)&xrs[0 ][colb + dq][8 * (q & 1)];
    u16x8 lf2 = *(const u16x8*)&xrs[dq][colb     ][8 * (q & 1)];
    u16x8 lf3 = *(const u16x8*)&xrs[1 ][colb + dq][8 * (q & 1)];

    // Store one output row (y = 2i+py): px=0 result pairs with px=1 result -> float2/lane.
    auto epi2 = [&](f32x4 hi0, f32x4 lo0, f32x4 hi1, f32x4 lo1, int py) {
      int y  = 2 * i + py;
      int xc = 2 * (j0 + jt + n);
      float2 mk = *(const float2*)&mask[((b * 512 + y) << 9) + xc];
      #pragma unroll
      for (int reg = 0; reg < 4; ++reg) {       // D: row(och) = 16*wid+4q+reg, col(pix) = lane&15
        int oc = 16 * wid + 4 * q + reg;
        float h0 = hi0[reg] + hb4[reg], l0 = lo0[reg] + lb4[reg];
        float h1 = hi1[reg] + hb4[reg], l1 = lo1[reg] + lb4[reg];
        float2 o;
        o.x = l0 + mk.x * (h0 - l0);
        o.y = l1 + mk.y * (h1 - l1);
        *(float2*)&out[((size_t)(b * 64 + oc) << 18) + ((size_t)y << 9) + xc] = o;
      }
    };

    const f32x4 z4 = {0.f, 0.f, 0.f, 0.f};
    f32x4 h0, l0, h1, l1;
    // ---- y row py=0 ----
    // phase (0,0): w(1,1)@(i,j)
    h0 = z4; l0 = z4;
    MF(h0, bh[4][0], ah[0][0][0]); MF(h0, bh[4][1], ah[0][0][1]);
    MF(l0, bl[0], lf0);
    // phase (0,1): w(1,0)@(i,j+1) + w(1,2)@(i,j)
    h1 = z4; l1 = z4;
    MF(h1, bh[3][0], ah[0][1][0]); MF(h1, bh[3][1], ah[0][1][1]);
    MF(h1, bh[5][0], ah[0][0][0]); MF(h1, bh[5][1], ah[0][0][1]);
    MF(l1, bl[1], lf1);
    epi2(h0, l0, h1, l1, 0);
    // ---- y row py=1 ----
    // phase (1,0): w(0,1)@(i+1,j) + w(2,1)@(i,j)
    h0 = z4; l0 = z4;
    MF(h0, bh[1][0], ah[1][0][0]); MF(h0, bh[1][1], ah[1][0][1]);
    MF(h0, bh[7][0], ah[0][0][0]); MF(h0, bh[7][1], ah[0][0][1]);
    MF(l0, bl[2], lf2);
    // phase (1,1): w(0,0)@(i+1,j+1) + w(0,2)@(i+1,j) + w(2,0)@(i,j+1) + w(2,2)@(i,j)
    h1 = z4; l1 = z4;
    MF(h1, bh[0][0], ah[1][1][0]); MF(h1, bh[0][1], ah[1][1][1]);
    MF(h1, bh[2][0], ah[1][0][0]); MF(h1, bh[2][1], ah[1][0][1]);
    MF(h1, bh[6][0], ah[0][1][0]); MF(h1, bh[6][1], ah[0][1][1]);
    MF(h1, bh[8][0], ah[0][0][0]); MF(h1, bh[8][1], ah[0][0][1]);
    MF(l1, bl[3], lf3); MF(l1, bl[4], lf1);
    epi2(h0, l0, h1, l1, 1);
  }
}

extern "C" void kernel_launch(void* const* d_in, const int* in_sizes, int n_in,
                              void* d_out, int out_size, void* d_ws, size_t ws_size,
                              hipStream_t stream)
{
  const float* x    = (const float*)d_in[0];
  const float* mask = (const float*)d_in[1];
  // d_in[2] = inv_mask, unused (mask is exactly 0.0/1.0)
  const float* hw   = (const float*)d_in[3];
  const float* hb   = (const float*)d_in[4];
  const float* l1w  = (const float*)d_in[5];
  const float* l1b  = (const float*)d_in[6];
  const float* l2w  = (const float*)d_in[7];
  const float* l2b  = (const float*)d_in[8];
  float* out = (float*)d_out;
  u16* ws  = (u16*)d_ws;
  u16* xr  = ws;                 // 4*256*256*16 = 4194304 elems (bf16)
  u16* whi = ws + 4194304;       // 36864 elems
  u16* wlo = whi + 36864;        // 10240 elems

  wprep<<<184, 256, 0, stream>>>(hw, l2w, whi, wlo);
  xr_kernel<<<1024, 256, 0, stream>>>(x, l1w, l1b, xr);
  tconv_main<<<dim3(4, 256, 4), 256, 0, stream>>>(x, xr, whi, wlo, mask, hb, l2b, out);
}

// Round 2
// 411.179 us; speedup vs baseline: 1.0825x; 1.0337x over previous
//
#include <hip/hip_runtime.h>

// Masked dual-branch ConvTranspose2d (stride 2, k3, pad 1, outpad 1), fp32 in/out.
//   out = mask ? (tconv(x, high_w)+hb) : (tconv(xr, low2_w)+lb),  xr = 1x1(x, low1_w)+l1b
// Internally: weights/x-tiles/xr downcast to bf16, mfma_f32_16x16x32_bf16, f32 accum.
// d_ws layout (u16 elems): [0, 36864) whi frags | [36864, +10240) wlo frags | [47104, +1024) w1 frags
//
// R1: MFMA operands swapped (weights as A, pixels as B) -> D[row=och][col=pixel];
//     epilogue stores float2/lane, 128B-contiguous per och. (-20 us)
// R2: xr_kernel FUSED into tconv_main: xrs computed in-LDS from the staged xs tile
//     via 2 MFMAs per 16-pixel tile (w1 in A-frag layout from wprep). Removes the
//     67 MB x re-read + 8.4 MB ws write + 17 MB ws read + one dispatch.

typedef unsigned short u16;
typedef unsigned int   u32;
typedef __bf16 bf16x8 __attribute__((ext_vector_type(8)));
typedef u16    u16x8  __attribute__((ext_vector_type(8)));
typedef float  f32x4  __attribute__((ext_vector_type(4)));

#define DEV static __device__ __forceinline__

DEV u16   f2bf(float f){ u32 u = __builtin_bit_cast(u32, f); u += 0x7FFF + ((u >> 16) & 1); return (u16)(u >> 16); }
DEV bf16x8 asb(u16x8 v){ return __builtin_bit_cast(bf16x8, v); }
// first frag arg is the MFMA A operand (rows of D), second is B (cols of D)
#define MF(acc, A, B) acc = __builtin_amdgcn_mfma_f32_16x16x32_bf16(asb(A), asb(B), acc, 0, 0, 0)

// ---------------- kernel 0: pre-shuffle weights into MFMA fragment order (f32 -> bf16) ----------------
// whi[(tap*2+Q)*4 + tile][lane][e] = bf16(high_w[c=32Q+8*(lane>>4)+e][och=16*tile+(lane&15)][kh][kw])
// wlo[f][tile][lane][e]: packed 2-tap (16ch each) frags; quads 0,1 = tapA, quads 2,3 = tapB.
// w1f[Q][lane][e] = bf16(low1_w[och=lane&15][c=32Q+8*(lane>>4)+e])  (A-frag for the 1x1 reduce)
__global__ __launch_bounds__(256) void wprep(const float* __restrict__ hw, const float* __restrict__ lw,
                                             const float* __restrict__ l1w,
                                             u16* __restrict__ whi, u16* __restrict__ wlo,
                                             u16* __restrict__ w1f)
{
  int t = blockIdx.x * 256 + threadIdx.x;
  if (t < 36864) {
    int e = t & 7, lane = (t >> 3) & 63, tile = (t >> 9) & 3, Q = (t >> 11) & 1, tap = t >> 12;
    int q = lane >> 4, n = lane & 15;
    int c = 32 * Q + 8 * q + e, och = 16 * tile + n;
    whi[t] = f2bf(hw[(c * 64 + och) * 9 + tap]);
  } else if (t < 47104) {
    int t2 = t - 36864;
    int e = t2 & 7, lane = (t2 >> 3) & 63, tile = (t2 >> 9) & 3, f = t2 >> 11;
    int q = lane >> 4, n = lane & 15, och = 16 * tile + n;
    // f: {P00:(1,1)|zero, P01:(1,0)|(1,2), P10:(0,1)|(2,1), P11a:(0,0)|(0,2), P11b:(2,0)|(2,2)}
    const int ta[10] = {4, -1, 3, 5, 1, 7, 0, 2, 6, 8};
    int tap = ta[f * 2 + (q >> 1)];
    u16 v = 0;
    if (tap >= 0) { int c = 8 * (q & 1) + e; v = f2bf(lw[(c * 64 + och) * 9 + tap]); }
    wlo[t2] = v;
  } else if (t < 48128) {
    int t3 = t - 47104;
    int e = t3 & 7, lane = (t3 >> 3) & 63, Q = t3 >> 9;
    int q = lane >> 4, n = lane & 15;
    w1f[t3] = f2bf(l1w[n * 64 + 32 * Q + 8 * q + e]);
  }
}

// ---------------- kernel 1: fused 1x1-reduce + 4-phase tconv + blend ----------------
// Block: (jchunk, i, b). Output rows 2i,2i+1, cols 2*j0..2*j0+127, all 64 och.
// Wave w -> och tile 16w. D row = och(4q+reg), col = pixel(lane&15).
__global__ __launch_bounds__(256) void tconv_main(
    const float* __restrict__ x,
    const u16* __restrict__ whi, const u16* __restrict__ wlo, const u16* __restrict__ w1f,
    const float* __restrict__ mask, const float* __restrict__ hbp,
    const float* __restrict__ lbp, const float* __restrict__ l1bp,
    float* __restrict__ out)
{
  __shared__ __attribute__((aligned(16))) u16 xs [2][68][72];  // [row][col][ch64 pad72] 144B col stride
  __shared__ __attribute__((aligned(16))) u16 xrs[2][68][24];  // [row][col][ch16 pad24]; ch16..23 zeroed

  const int tid  = threadIdx.x;
  const int lane = tid & 63, wid = tid >> 6;
  const int j0 = blockIdx.x * 64;
  const int i  = blockIdx.y;
  const int b  = blockIdx.z;
  const int q  = lane >> 4, n = lane & 15;

  // ---- phase 1: stage x rows {i,i+1}, cols j0..j0+64, downcast bf16, transpose to ch-contiguous ----
  for (int idx = tid; idx < 2 * 64 * 32; idx += 256) {
    int cp = idx & 31, c = (idx >> 5) & 63, row = idx >> 11;
    int gi = i + row, col = cp * 2;
    float2 v = make_float2(0.f, 0.f);
    if (gi < 256) v = *(const float2*)&x[((size_t)b << 22) + ((size_t)c << 16) + (gi << 8) + (j0 + col)];
    xs[row][col    ][c] = f2bf(v.x);
    xs[row][col + 1][c] = f2bf(v.y);
  }
  if (tid < 128) {  // halo col 64
    int row = tid >> 6, c = tid & 63, gi = i + row, gj = j0 + 64;
    float v = 0.f;
    if (gi < 256 && gj < 256) v = x[((size_t)b << 22) + ((size_t)c << 16) + (gi << 8) + gj];
    xs[row][64][c] = f2bf(v);
  }
  if (tid < 136) {  // zero pad channels 16..23 of xrs (zero half of the P00 low frag)
    int row = tid / 68, col = tid % 68;
    *(uint4*)&xrs[row][col][16] = make_uint4(0, 0, 0, 0);
  }
  __syncthreads();

  // ---- phase 1b: xrs[row][col][0..15] = bf16(W1 (16x64) @ xs + l1b), in-LDS via MFMA ----
  // 130 needed pixels (2 rows x cols 0..64) mapped p = row*72+col, 9 tiles of 16 pixels.
  {
    const u16x8* w1f8 = (const u16x8*)w1f;
    u16x8 aw0 = w1f8[lane], aw1 = w1f8[64 + lane];
    float b14[4];
    #pragma unroll
    for (int r = 0; r < 4; ++r) b14[r] = l1bp[4 * q + r];
    #pragma unroll
    for (int tt = 0; tt < 3; ++tt) {
      int tile = wid + 4 * tt;          // wave-uniform
      if (tile < 9) {
        int p = 16 * tile + n;
        int row = (p >= 72) ? 1 : 0;
        int col = p - 72 * row;
        int colr = (col < 68) ? col : 67;   // clamp: lanes with col>=65 are discarded
        f32x4 d = {0.f, 0.f, 0.f, 0.f};
        MF(d, aw0, *(const u16x8*)&xs[row][colr][8 * q]);
        MF(d, aw1, *(const u16x8*)&xs[row][colr][32 + 8 * q]);
        if (col < 65) {                  // only cols 0..64 are ever consumed
          int gi = i + row, gj = j0 + col;
          u32 pk0 = 0, pk1 = 0;
          if (gi < 256 && gj < 256) {    // out-of-range input pixel => conv sees ZERO (not bias)
            pk0 = (u32)f2bf(d[0] + b14[0]) | ((u32)f2bf(d[1] + b14[1]) << 16);
            pk1 = (u32)f2bf(d[2] + b14[2]) | ((u32)f2bf(d[3] + b14[3]) << 16);
          }
          *(uint2*)&xrs[row][col][4 * q] = make_uint2(pk0, pk1);  // och 4q..4q+3
        }
      }
    }
  }

  // ---- weight fragments in registers (coalesced 16B/lane from pre-shuffled layout) ----
  u16x8 bh[9][2], bl[5];
  {
    const u16x8* wh8 = (const u16x8*)whi;
    #pragma unroll
    for (int tap = 0; tap < 9; ++tap)
      #pragma unroll
      for (int Q = 0; Q < 2; ++Q)
        bh[tap][Q] = wh8[((tap * 2 + Q) * 4 + wid) * 64 + lane];
    const u16x8* wl8 = (const u16x8*)wlo;
    #pragma unroll
    for (int f = 0; f < 5; ++f) bl[f] = wl8[(f * 4 + wid) * 64 + lane];
  }
  // Per-lane biases: this lane's D rows are och = 16*wid + 4*q + reg.
  float hb4[4], lb4[4];
  #pragma unroll
  for (int r = 0; r < 4; ++r) {
    hb4[r] = hbp[16 * wid + 4 * q + r];
    lb4[r] = lbp[16 * wid + 4 * q + r];
  }
  __syncthreads();

  #pragma unroll
  for (int jt = 0; jt < 64; jt += 16) {
    const int colb = jt + n;   // B-frag: pixel n = lane&15
    u16x8 ah[2][2][2];         // [row][dx][Q]
    #pragma unroll
    for (int r = 0; r < 2; ++r)
      #pragma unroll
      for (int d = 0; d < 2; ++d)
        #pragma unroll
        for (int Q = 0; Q < 2; ++Q)
          ah[r][d][Q] = *(const u16x8*)&xs[r][colb + d][32 * Q + 8 * q];
    const int dq = (q < 2) ? 1 : 0;  // quads 0,1 = tapA / quads 2,3 = tapB
    u16x8 lf0 = *(const u16x8*)&xrs[0 ][colb     ][(q < 2) ? 8 * (q & 1) : 16];
    u16x8 lf1 = *(const u16x8*)&xrs[0 ][colb + dq][8 * (q & 1)];
    u16x8 lf2 = *(const u16x8*)&xrs[dq][colb     ][8 * (q & 1)];
    u16x8 lf3 = *(const u16x8*)&xrs[1 ][colb + dq][8 * (q & 1)];

    // Store one output row (y = 2i+py): px=0 result pairs with px=1 result -> float2/lane.
    auto epi2 = [&](f32x4 hi0, f32x4 lo0, f32x4 hi1, f32x4 lo1, int py) {
      int y  = 2 * i + py;
      int xc = 2 * (j0 + jt + n);
      float2 mk = *(const float2*)&mask[((b * 512 + y) << 9) + xc];
      #pragma unroll
      for (int reg = 0; reg < 4; ++reg) {       // D: row(och) = 16*wid+4q+reg, col(pix) = lane&15
        int oc = 16 * wid + 4 * q + reg;
        float h0 = hi0[reg] + hb4[reg], l0 = lo0[reg] + lb4[reg];
        float h1 = hi1[reg] + hb4[reg], l1 = lo1[reg] + lb4[reg];
        float2 o;
        o.x = l0 + mk.x * (h0 - l0);
        o.y = l1 + mk.y * (h1 - l1);
        *(float2*)&out[((size_t)(b * 64 + oc) << 18) + ((size_t)y << 9) + xc] = o;
      }
    };

    const f32x4 z4 = {0.f, 0.f, 0.f, 0.f};
    f32x4 h0, l0, h1, l1;
    // ---- y row py=0 ----
    // phase (0,0): w(1,1)@(i,j)
    h0 = z4; l0 = z4;
    MF(h0, bh[4][0], ah[0][0][0]); MF(h0, bh[4][1], ah[0][0][1]);
    MF(l0, bl[0], lf0);
    // phase (0,1): w(1,0)@(i,j+1) + w(1,2)@(i,j)
    h1 = z4; l1 = z4;
    MF(h1, bh[3][0], ah[0][1][0]); MF(h1, bh[3][1], ah[0][1][1]);
    MF(h1, bh[5][0], ah[0][0][0]); MF(h1, bh[5][1], ah[0][0][1]);
    MF(l1, bl[1], lf1);
    epi2(h0, l0, h1, l1, 0);
    // ---- y row py=1 ----
    // phase (1,0): w(0,1)@(i+1,j) + w(2,1)@(i,j)
    h0 = z4; l0 = z4;
    MF(h0, bh[1][0], ah[1][0][0]); MF(h0, bh[1][1], ah[1][0][1]);
    MF(h0, bh[7][0], ah[0][0][0]); MF(h0, bh[7][1], ah[0][0][1]);
    MF(l0, bl[2], lf2);
    // phase (1,1): w(0,0)@(i+1,j+1) + w(0,2)@(i+1,j) + w(2,0)@(i,j+1) + w(2,2)@(i,j)
    h1 = z4; l1 = z4;
    MF(h1, bh[0][0], ah[1][1][0]); MF(h1, bh[0][1], ah[1][1][1]);
    MF(h1, bh[2][0], ah[1][0][0]); MF(h1, bh[2][1], ah[1][0][1]);
    MF(h1, bh[6][0], ah[0][1][0]); MF(h1, bh[6][1], ah[0][1][1]);
    MF(h1, bh[8][0], ah[0][0][0]); MF(h1, bh[8][1], ah[0][0][1]);
    MF(l1, bl[3], lf3); MF(l1, bl[4], lf1);
    epi2(h0, l0, h1, l1, 1);
  }
}

extern "C" void kernel_launch(void* const* d_in, const int* in_sizes, int n_in,
                              void* d_out, int out_size, void* d_ws, size_t ws_size,
                              hipStream_t stream)
{
  const float* x    = (const float*)d_in[0];
  const float* mask = (const float*)d_in[1];
  // d_in[2] = inv_mask, unused (mask is exactly 0.0/1.0)
  const float* hw   = (const float*)d_in[3];
  const float* hb   = (const float*)d_in[4];
  const float* l1w  = (const float*)d_in[5];
  const float* l1b  = (const float*)d_in[6];
  const float* l2w  = (const float*)d_in[7];
  const float* l2b  = (const float*)d_in[8];
  float* out = (float*)d_out;
  u16* ws  = (u16*)d_ws;
  u16* whi = ws;                 // 36864 elems
  u16* wlo = whi + 36864;        // 10240 elems
  u16* w1f = whi + 47104;        // 1024 elems

  wprep<<<188, 256, 0, stream>>>(hw, l2w, l1w, whi, wlo, w1f);
  tconv_main<<<dim3(4, 256, 4), 256, 0, stream>>>(x, whi, wlo, w1f, mask, hb, l2b, l1b, out);
}

// Round 3
// 372.794 us; speedup vs baseline: 1.1940x; 1.1030x over previous
//
#include <hip/hip_runtime.h>

// Masked dual-branch ConvTranspose2d (stride 2, k3, pad 1, outpad 1), fp32 in/out.
//   out = mask ? (tconv(x, high_w)+hb) : (tconv(xr, low2_w)+lb),  xr = 1x1(x, low1_w)+l1b
// Internally: weights/x-tiles/xr downcast to bf16, mfma_f32_16x16x32_bf16, f32 accum.
// d_ws layout (u16 elems): [0, 36864) whi frags | [36864, +10240) wlo frags | [47104, +1024) w1 frags
//
// R1: MFMA operands swapped -> D[row=och][col=pixel]; float2/lane coalesced stores. (-20 us)
// R2: 1x1 reduce fused in-LDS (2 MFMAs/16-pixel tile); xr_kernel deleted. (-14 us)
// R3: IBLK=2 (block does i,i+1 -> 4 output rows): halves block count & weight-frag L2
//     traffic, row-stage overlap 2x -> 1.5x; float4 staging loads; nontemporal out stores.

typedef unsigned short u16;
typedef unsigned int   u32;
typedef __bf16 bf16x8 __attribute__((ext_vector_type(8)));
typedef u16    u16x8  __attribute__((ext_vector_type(8)));
typedef float  f32x4  __attribute__((ext_vector_type(4)));
typedef float  f32x2  __attribute__((ext_vector_type(2)));

#define DEV static __device__ __forceinline__

DEV u16   f2bf(float f){ u32 u = __builtin_bit_cast(u32, f); u += 0x7FFF + ((u >> 16) & 1); return (u16)(u >> 16); }
DEV bf16x8 asb(u16x8 v){ return __builtin_bit_cast(bf16x8, v); }
// first frag arg is the MFMA A operand (rows of D), second is B (cols of D)
#define MF(acc, A, B) acc = __builtin_amdgcn_mfma_f32_16x16x32_bf16(asb(A), asb(B), acc, 0, 0, 0)

// ---------------- kernel 0: pre-shuffle weights into MFMA fragment order (f32 -> bf16) ----------------
// whi[(tap*2+Q)*4 + tile][lane][e] = bf16(high_w[c=32Q+8*(lane>>4)+e][och=16*tile+(lane&15)][kh][kw])
// wlo[f][tile][lane][e]: packed 2-tap (16ch each) frags; quads 0,1 = tapA, quads 2,3 = tapB.
// w1f[Q][lane][e] = bf16(low1_w[och=lane&15][c=32Q+8*(lane>>4)+e])  (A-frag for the 1x1 reduce)
__global__ __launch_bounds__(256) void wprep(const float* __restrict__ hw, const float* __restrict__ lw,
                                             const float* __restrict__ l1w,
                                             u16* __restrict__ whi, u16* __restrict__ wlo,
                                             u16* __restrict__ w1f)
{
  int t = blockIdx.x * 256 + threadIdx.x;
  if (t < 36864) {
    int e = t & 7, lane = (t >> 3) & 63, tile = (t >> 9) & 3, Q = (t >> 11) & 1, tap = t >> 12;
    int q = lane >> 4, n = lane & 15;
    int c = 32 * Q + 8 * q + e, och = 16 * tile + n;
    whi[t] = f2bf(hw[(c * 64 + och) * 9 + tap]);
  } else if (t < 47104) {
    int t2 = t - 36864;
    int e = t2 & 7, lane = (t2 >> 3) & 63, tile = (t2 >> 9) & 3, f = t2 >> 11;
    int q = lane >> 4, n = lane & 15, och = 16 * tile + n;
    // f: {P00:(1,1)|zero, P01:(1,0)|(1,2), P10:(0,1)|(2,1), P11a:(0,0)|(0,2), P11b:(2,0)|(2,2)}
    const int ta[10] = {4, -1, 3, 5, 1, 7, 0, 2, 6, 8};
    int tap = ta[f * 2 + (q >> 1)];
    u16 v = 0;
    if (tap >= 0) { int c = 8 * (q & 1) + e; v = f2bf(lw[(c * 64 + och) * 9 + tap]); }
    wlo[t2] = v;
  } else if (t < 48128) {
    int t3 = t - 47104;
    int e = t3 & 7, lane = (t3 >> 3) & 63, Q = t3 >> 9;
    int q = lane >> 4, n = lane & 15;
    w1f[t3] = f2bf(l1w[n * 64 + 32 * Q + 8 * q + e]);
  }
}

// ---------------- kernel 1: fused 1x1-reduce + 4-phase tconv + blend, IBLK=2 ----------------
// Block: (jchunk, ib, b). i = 2*ib + iv (iv=0,1). Output rows 4*ib..4*ib+3, cols 2*j0..2*j0+127.
// Wave w -> och tile 16w. D row = och(4q+reg), col = pixel(lane&15).
__global__ __launch_bounds__(256) void tconv_main(
    const float* __restrict__ x,
    const u16* __restrict__ whi, const u16* __restrict__ wlo, const u16* __restrict__ w1f,
    const float* __restrict__ mask, const float* __restrict__ hbp,
    const float* __restrict__ lbp, const float* __restrict__ l1bp,
    float* __restrict__ out)
{
  __shared__ __attribute__((aligned(16))) u16 xs [3][68][72];  // [row][col][ch64 pad72] 144B col stride
  __shared__ __attribute__((aligned(16))) u16 xrs[3][68][24];  // [row][col][ch16 pad24]; ch16..23 zeroed

  const int tid  = threadIdx.x;
  const int lane = tid & 63, wid = tid >> 6;
  const int j0 = blockIdx.x * 64;
  const int ib = blockIdx.y;                 // covers input rows 2ib..2ib+2
  const int b  = blockIdx.z;
  const int q  = lane >> 4, n = lane & 15;

  // ---- stage x rows {2ib..2ib+2}, cols j0..j0+64, downcast bf16, transpose to ch-contiguous ----
  for (int idx = tid; idx < 3 * 64 * 16; idx += 256) {   // float4 per lane
    int f4 = idx & 15, c = (idx >> 4) & 63, row = idx >> 10;
    int gi = 2 * ib + row, col = 4 * f4;
    float4 v = make_float4(0.f, 0.f, 0.f, 0.f);
    if (gi < 256) v = *(const float4*)&x[((size_t)b << 22) + ((size_t)c << 16) + (gi << 8) + (j0 + col)];
    xs[row][col    ][c] = f2bf(v.x);
    xs[row][col + 1][c] = f2bf(v.y);
    xs[row][col + 2][c] = f2bf(v.z);
    xs[row][col + 3][c] = f2bf(v.w);
  }
  if (tid < 192) {  // halo col 64
    int row = tid >> 6, c = tid & 63, gi = 2 * ib + row, gj = j0 + 64;
    float v = 0.f;
    if (gi < 256 && gj < 256) v = x[((size_t)b << 22) + ((size_t)c << 16) + (gi << 8) + gj];
    xs[row][64][c] = f2bf(v);
  }
  if (tid < 204) {  // zero pad channels 16..23 of xrs (zero half of the P00 low frag)
    int row = tid / 68, col = tid % 68;
    *(uint4*)&xrs[row][col][16] = make_uint4(0, 0, 0, 0);
  }
  __syncthreads();

  // ---- xrs[row][col][0..15] = bf16(W1 (16x64) @ xs + l1b), in-LDS via MFMA ----
  // 195 needed pixels (3 rows x cols 0..64), mapped p = row*72+col, 14 tiles of 16.
  {
    const u16x8* w1f8 = (const u16x8*)w1f;
    u16x8 aw0 = w1f8[lane], aw1 = w1f8[64 + lane];
    float b14[4];
    #pragma unroll
    for (int r = 0; r < 4; ++r) b14[r] = l1bp[4 * q + r];
    #pragma unroll
    for (int tt = 0; tt < 4; ++tt) {
      int tile = wid + 4 * tt;          // wave-uniform
      if (tile < 14) {
        int p = 16 * tile + n;
        int row = (p >= 144) ? 2 : ((p >= 72) ? 1 : 0);
        int col = p - 72 * row;
        int colr = (col < 68) ? col : 67;   // clamp: lanes with col>=65 are discarded
        f32x4 d = {0.f, 0.f, 0.f, 0.f};
        MF(d, aw0, *(const u16x8*)&xs[row][colr][8 * q]);
        MF(d, aw1, *(const u16x8*)&xs[row][colr][32 + 8 * q]);
        if (col < 65) {                  // only cols 0..64 are ever consumed
          int gi = 2 * ib + row, gj = j0 + col;
          u32 pk0 = 0, pk1 = 0;
          if (gi < 256 && gj < 256) {    // out-of-range input pixel => conv sees ZERO (not bias)
            pk0 = (u32)f2bf(d[0] + b14[0]) | ((u32)f2bf(d[1] + b14[1]) << 16);
            pk1 = (u32)f2bf(d[2] + b14[2]) | ((u32)f2bf(d[3] + b14[3]) << 16);
          }
          *(uint2*)&xrs[row][col][4 * q] = make_uint2(pk0, pk1);  // och 4q..4q+3
        }
      }
    }
  }

  // ---- weight fragments in registers (coalesced 16B/lane from pre-shuffled layout) ----
  u16x8 bh[9][2], bl[5];
  {
    const u16x8* wh8 = (const u16x8*)whi;
    #pragma unroll
    for (int tap = 0; tap < 9; ++tap)
      #pragma unroll
      for (int Q = 0; Q < 2; ++Q)
        bh[tap][Q] = wh8[((tap * 2 + Q) * 4 + wid) * 64 + lane];
    const u16x8* wl8 = (const u16x8*)wlo;
    #pragma unroll
    for (int f = 0; f < 5; ++f) bl[f] = wl8[(f * 4 + wid) * 64 + lane];
  }
  // Per-lane biases: this lane's D rows are och = 16*wid + 4*q + reg.
  float hb4[4], lb4[4];
  #pragma unroll
  for (int r = 0; r < 4; ++r) {
    hb4[r] = hbp[16 * wid + 4 * q + r];
    lb4[r] = lbp[16 * wid + 4 * q + r];
  }
  __syncthreads();

  #pragma unroll 1
  for (int iv = 0; iv < 2; ++iv) {
    #pragma unroll
    for (int jt = 0; jt < 64; jt += 16) {
      const int colb = jt + n;   // B-frag: pixel n = lane&15
      u16x8 ah[2][2][2];         // [row][dx][Q]
      #pragma unroll
      for (int r = 0; r < 2; ++r)
        #pragma unroll
        for (int d = 0; d < 2; ++d)
          #pragma unroll
          for (int Q = 0; Q < 2; ++Q)
            ah[r][d][Q] = *(const u16x8*)&xs[iv + r][colb + d][32 * Q + 8 * q];
      const int dq = (q < 2) ? 1 : 0;  // quads 0,1 = tapA / quads 2,3 = tapB
      u16x8 lf0 = *(const u16x8*)&xrs[iv     ][colb     ][(q < 2) ? 8 * (q & 1) : 16];
      u16x8 lf1 = *(const u16x8*)&xrs[iv     ][colb + dq][8 * (q & 1)];
      u16x8 lf2 = *(const u16x8*)&xrs[iv + dq][colb     ][8 * (q & 1)];
      u16x8 lf3 = *(const u16x8*)&xrs[iv + 1 ][colb + dq][8 * (q & 1)];

      // Store one output row: px=0 result pairs with px=1 result -> float2/lane, nontemporal.
      auto epi2 = [&](f32x4 hi0, f32x4 lo0, f32x4 hi1, f32x4 lo1, int py) {
        int y  = 4 * ib + 2 * iv + py;
        int xc = 2 * (j0 + jt + n);
        float2 mk = *(const float2*)&mask[((b * 512 + y) << 9) + xc];
        #pragma unroll
        for (int reg = 0; reg < 4; ++reg) {     // D: row(och) = 16*wid+4q+reg, col(pix) = lane&15
          int oc = 16 * wid + 4 * q + reg;
          float h0 = hi0[reg] + hb4[reg], l0 = lo0[reg] + lb4[reg];
          float h1 = hi1[reg] + hb4[reg], l1 = lo1[reg] + lb4[reg];
          f32x2 o;
          o.x = l0 + mk.x * (h0 - l0);
          o.y = l1 + mk.y * (h1 - l1);
          __builtin_nontemporal_store(o, (f32x2*)&out[((size_t)(b * 64 + oc) << 18) + ((size_t)y << 9) + xc]);
        }
      };

      const f32x4 z4 = {0.f, 0.f, 0.f, 0.f};
      f32x4 h0, l0, h1, l1;
      // ---- y row py=0 ----
      // phase (0,0): w(1,1)@(i,j)
      h0 = z4; l0 = z4;
      MF(h0, bh[4][0], ah[0][0][0]); MF(h0, bh[4][1], ah[0][0][1]);
      MF(l0, bl[0], lf0);
      // phase (0,1): w(1,0)@(i,j+1) + w(1,2)@(i,j)
      h1 = z4; l1 = z4;
      MF(h1, bh[3][0], ah[0][1][0]); MF(h1, bh[3][1], ah[0][1][1]);
      MF(h1, bh[5][0], ah[0][0][0]); MF(h1, bh[5][1], ah[0][0][1]);
      MF(l1, bl[1], lf1);
      epi2(h0, l0, h1, l1, 0);
      // ---- y row py=1 ----
      // phase (1,0): w(0,1)@(i+1,j) + w(2,1)@(i,j)
      h0 = z4; l0 = z4;
      MF(h0, bh[1][0], ah[1][0][0]); MF(h0, bh[1][1], ah[1][0][1]);
      MF(h0, bh[7][0], ah[0][0][0]); MF(h0, bh[7][1], ah[0][0][1]);
      MF(l0, bl[2], lf2);
      // phase (1,1): w(0,0)@(i+1,j+1) + w(0,2)@(i+1,j) + w(2,0)@(i,j+1) + w(2,2)@(i,j)
      h1 = z4; l1 = z4;
      MF(h1, bh[0][0], ah[1][1][0]); MF(h1, bh[0][1], ah[1][1][1]);
      MF(h1, bh[2][0], ah[1][0][0]); MF(h1, bh[2][1], ah[1][0][1]);
      MF(h1, bh[6][0], ah[0][1][0]); MF(h1, bh[6][1], ah[0][1][1]);
      MF(h1, bh[8][0], ah[0][0][0]); MF(h1, bh[8][1], ah[0][0][1]);
      MF(l1, bl[3], lf3); MF(l1, bl[4], lf1);
      epi2(h0, l0, h1, l1, 1);
    }
  }
}

extern "C" void kernel_launch(void* const* d_in, const int* in_sizes, int n_in,
                              void* d_out, int out_size, void* d_ws, size_t ws_size,
                              hipStream_t stream)
{
  const float* x    = (const float*)d_in[0];
  const float* mask = (const float*)d_in[1];
  // d_in[2] = inv_mask, unused (mask is exactly 0.0/1.0)
  const float* hw   = (const float*)d_in[3];
  const float* hb   = (const float*)d_in[4];
  const float* l1w  = (const float*)d_in[5];
  const float* l1b  = (const float*)d_in[6];
  const float* l2w  = (const float*)d_in[7];
  const float* l2b  = (const float*)d_in[8];
  float* out = (float*)d_out;
  u16* ws  = (u16*)d_ws;
  u16* whi = ws;                 // 36864 elems
  u16* wlo = whi + 36864;        // 10240 elems
  u16* w1f = whi + 47104;        // 1024 elems

  wprep<<<188, 256, 0, stream>>>(hw, l2w, l1w, whi, wlo, w1f);
  tconv_main<<<dim3(4, 128, 4), 256, 0, stream>>>(x, whi, wlo, w1f, mask, hb, l2b, l1b, out);
}

// Round 4
// 370.590 us; speedup vs baseline: 1.2011x; 1.0059x over previous
//
#include <hip/hip_runtime.h>

// Masked dual-branch ConvTranspose2d (stride 2, k3, pad 1, outpad 1), fp32 in/out.
//   out = mask ? (tconv(x, high_w)+hb) : (tconv(xr, low2_w)+lb),  xr = 1x1(x, low1_w)+l1b
// Internally: weights/x-tiles/xr downcast to bf16, mfma_f32_16x16x32_bf16, f32 accum.
// d_ws layout (u16 elems): [0, 36864) whi frags | [36864, +10240) wlo frags | [47104, +1024) w1 frags
//
// R1: MFMA operands swapped -> D[row=och][col=pixel]; float2/lane coalesced stores. (-20 us)
// R2: 1x1 reduce fused in-LDS; xr_kernel deleted. (-14 us)
// R3: IBLK=2, float4 staging, nontemporal stores. (-38 us)
// R4: IBLK=4 (block does input rows 4ib..4ib+3 -> 8 output rows): blocks 2048->1024,
//     weight-frag L2 traffic halved, x-stage overlap 1.5x->1.25x. LDS 65,280 B
//     (2 blocks/CU). Probe to disambiguate remaining controllable share.

typedef unsigned short u16;
typedef unsigned int   u32;
typedef __bf16 bf16x8 __attribute__((ext_vector_type(8)));
typedef u16    u16x8  __attribute__((ext_vector_type(8)));
typedef float  f32x4  __attribute__((ext_vector_type(4)));
typedef float  f32x2  __attribute__((ext_vector_type(2)));

#define DEV static __device__ __forceinline__

DEV u16   f2bf(float f){ u32 u = __builtin_bit_cast(u32, f); u += 0x7FFF + ((u >> 16) & 1); return (u16)(u >> 16); }
DEV bf16x8 asb(u16x8 v){ return __builtin_bit_cast(bf16x8, v); }
// first frag arg is the MFMA A operand (rows of D), second is B (cols of D)
#define MF(acc, A, B) acc = __builtin_amdgcn_mfma_f32_16x16x32_bf16(asb(A), asb(B), acc, 0, 0, 0)

// ---------------- kernel 0: pre-shuffle weights into MFMA fragment order (f32 -> bf16) ----------------
// whi[(tap*2+Q)*4 + tile][lane][e] = bf16(high_w[c=32Q+8*(lane>>4)+e][och=16*tile+(lane&15)][kh][kw])
// wlo[f][tile][lane][e]: packed 2-tap (16ch each) frags; quads 0,1 = tapA, quads 2,3 = tapB.
// w1f[Q][lane][e] = bf16(low1_w[och=lane&15][c=32Q+8*(lane>>4)+e])  (A-frag for the 1x1 reduce)
__global__ __launch_bounds__(256) void wprep(const float* __restrict__ hw, const float* __restrict__ lw,
                                             const float* __restrict__ l1w,
                                             u16* __restrict__ whi, u16* __restrict__ wlo,
                                             u16* __restrict__ w1f)
{
  int t = blockIdx.x * 256 + threadIdx.x;
  if (t < 36864) {
    int e = t & 7, lane = (t >> 3) & 63, tile = (t >> 9) & 3, Q = (t >> 11) & 1, tap = t >> 12;
    int q = lane >> 4, n = lane & 15;
    int c = 32 * Q + 8 * q + e, och = 16 * tile + n;
    whi[t] = f2bf(hw[(c * 64 + och) * 9 + tap]);
  } else if (t < 47104) {
    int t2 = t - 36864;
    int e = t2 & 7, lane = (t2 >> 3) & 63, tile = (t2 >> 9) & 3, f = t2 >> 11;
    int q = lane >> 4, n = lane & 15, och = 16 * tile + n;
    // f: {P00:(1,1)|zero, P01:(1,0)|(1,2), P10:(0,1)|(2,1), P11a:(0,0)|(0,2), P11b:(2,0)|(2,2)}
    const int ta[10] = {4, -1, 3, 5, 1, 7, 0, 2, 6, 8};
    int tap = ta[f * 2 + (q >> 1)];
    u16 v = 0;
    if (tap >= 0) { int c = 8 * (q & 1) + e; v = f2bf(lw[(c * 64 + och) * 9 + tap]); }
    wlo[t2] = v;
  } else if (t < 48128) {
    int t3 = t - 47104;
    int e = t3 & 7, lane = (t3 >> 3) & 63, Q = t3 >> 9;
    int q = lane >> 4, n = lane & 15;
    w1f[t3] = f2bf(l1w[n * 64 + 32 * Q + 8 * q + e]);
  }
}

// ---------------- kernel 1: fused 1x1-reduce + 4-phase tconv + blend, IBLK=4 ----------------
// Block: (jchunk, ib, b). i = 4*ib + iv (iv=0..3). Output rows 8*ib..8*ib+7, cols 2*j0..2*j0+127.
// Wave w -> och tile 16w. D row = och(4q+reg), col = pixel(lane&15).
__global__ __launch_bounds__(256) void tconv_main(
    const float* __restrict__ x,
    const u16* __restrict__ whi, const u16* __restrict__ wlo, const u16* __restrict__ w1f,
    const float* __restrict__ mask, const float* __restrict__ hbp,
    const float* __restrict__ lbp, const float* __restrict__ l1bp,
    float* __restrict__ out)
{
  __shared__ __attribute__((aligned(16))) u16 xs [5][68][72];  // [row][col][ch64 pad72] 144B col stride
  __shared__ __attribute__((aligned(16))) u16 xrs[5][68][24];  // [row][col][ch16 pad24]; ch16..23 zeroed

  const int tid  = threadIdx.x;
  const int lane = tid & 63, wid = tid >> 6;
  const int j0 = blockIdx.x * 64;
  const int ib = blockIdx.y;                 // covers input rows 4ib..4ib+4
  const int b  = blockIdx.z;
  const int q  = lane >> 4, n = lane & 15;

  // ---- stage x rows {4ib..4ib+4}, cols j0..j0+64, downcast bf16, transpose to ch-contiguous ----
  for (int idx = tid; idx < 5 * 64 * 16; idx += 256) {   // float4 per lane
    int f4 = idx & 15, c = (idx >> 4) & 63, row = idx >> 10;
    int gi = 4 * ib + row, col = 4 * f4;
    float4 v = make_float4(0.f, 0.f, 0.f, 0.f);
    if (gi < 256) v = *(const float4*)&x[((size_t)b << 22) + ((size_t)c << 16) + (gi << 8) + (j0 + col)];
    xs[row][col    ][c] = f2bf(v.x);
    xs[row][col + 1][c] = f2bf(v.y);
    xs[row][col + 2][c] = f2bf(v.z);
    xs[row][col + 3][c] = f2bf(v.w);
  }
  for (int u = tid; u < 5 * 64; u += 256) {  // halo col 64
    int row = u >> 6, c = u & 63, gi = 4 * ib + row, gj = j0 + 64;
    float v = 0.f;
    if (gi < 256 && gj < 256) v = x[((size_t)b << 22) + ((size_t)c << 16) + (gi << 8) + gj];
    xs[row][64][c] = f2bf(v);
  }
  for (int u = tid; u < 5 * 68; u += 256) {  // zero pad channels 16..23 of xrs (zero half of P00 low frag)
    int row = u / 68, col = u % 68;
    *(uint4*)&xrs[row][col][16] = make_uint4(0, 0, 0, 0);
  }
  __syncthreads();

  // ---- xrs[row][col][0..15] = bf16(W1 (16x64) @ xs + l1b), in-LDS via MFMA ----
  // 325 needed pixels (5 rows x cols 0..64), mapped p = row*72+col, 23 tiles of 16.
  {
    const u16x8* w1f8 = (const u16x8*)w1f;
    u16x8 aw0 = w1f8[lane], aw1 = w1f8[64 + lane];
    float b14[4];
    #pragma unroll
    for (int r = 0; r < 4; ++r) b14[r] = l1bp[4 * q + r];
    #pragma unroll
    for (int tt = 0; tt < 6; ++tt) {
      int tile = wid + 4 * tt;          // wave-uniform
      if (tile < 23) {
        int p = 16 * tile + n;
        int row = p / 72, col = p % 72;
        int colr = (col < 68) ? col : 67;   // clamp: lanes with col>=65 are discarded
        f32x4 d = {0.f, 0.f, 0.f, 0.f};
        MF(d, aw0, *(const u16x8*)&xs[row][colr][8 * q]);
        MF(d, aw1, *(const u16x8*)&xs[row][colr][32 + 8 * q]);
        if (col < 65) {                  // only cols 0..64 are ever consumed
          int gi = 4 * ib + row, gj = j0 + col;
          u32 pk0 = 0, pk1 = 0;
          if (gi < 256 && gj < 256) {    // out-of-range input pixel => conv sees ZERO (not bias)
            pk0 = (u32)f2bf(d[0] + b14[0]) | ((u32)f2bf(d[1] + b14[1]) << 16);
            pk1 = (u32)f2bf(d[2] + b14[2]) | ((u32)f2bf(d[3] + b14[3]) << 16);
          }
          *(uint2*)&xrs[row][col][4 * q] = make_uint2(pk0, pk1);  // och 4q..4q+3
        }
      }
    }
  }

  // ---- weight fragments in registers (coalesced 16B/lane from pre-shuffled layout) ----
  u16x8 bh[9][2], bl[5];
  {
    const u16x8* wh8 = (const u16x8*)whi;
    #pragma unroll
    for (int tap = 0; tap < 9; ++tap)
      #pragma unroll
      for (int Q = 0; Q < 2; ++Q)
        bh[tap][Q] = wh8[((tap * 2 + Q) * 4 + wid) * 64 + lane];
    const u16x8* wl8 = (const u16x8*)wlo;
    #pragma unroll
    for (int f = 0; f < 5; ++f) bl[f] = wl8[(f * 4 + wid) * 64 + lane];
  }
  // Per-lane biases: this lane's D rows are och = 16*wid + 4*q + reg.
  float hb4[4], lb4[4];
  #pragma unroll
  for (int r = 0; r < 4; ++r) {
    hb4[r] = hbp[16 * wid + 4 * q + r];
    lb4[r] = lbp[16 * wid + 4 * q + r];
  }
  __syncthreads();

  #pragma unroll 1
  for (int iv = 0; iv < 4; ++iv) {
    #pragma unroll
    for (int jt = 0; jt < 64; jt += 16) {
      const int colb = jt + n;   // B-frag: pixel n = lane&15
      u16x8 ah[2][2][2];         // [row][dx][Q]
      #pragma unroll
      for (int r = 0; r < 2; ++r)
        #pragma unroll
        for (int d = 0; d < 2; ++d)
          #pragma unroll
          for (int Q = 0; Q < 2; ++Q)
            ah[r][d][Q] = *(const u16x8*)&xs[iv + r][colb + d][32 * Q + 8 * q];
      const int dq = (q < 2) ? 1 : 0;  // quads 0,1 = tapA / quads 2,3 = tapB
      u16x8 lf0 = *(const u16x8*)&xrs[iv     ][colb     ][(q < 2) ? 8 * (q & 1) : 16];
      u16x8 lf1 = *(const u16x8*)&xrs[iv     ][colb + dq][8 * (q & 1)];
      u16x8 lf2 = *(const u16x8*)&xrs[iv + dq][colb     ][8 * (q & 1)];
      u16x8 lf3 = *(const u16x8*)&xrs[iv + 1 ][colb + dq][8 * (q & 1)];

      // Store one output row: px=0 result pairs with px=1 result -> float2/lane, nontemporal.
      auto epi2 = [&](f32x4 hi0, f32x4 lo0, f32x4 hi1, f32x4 lo1, int py) {
        int y  = 8 * ib + 2 * iv + py;
        int xc = 2 * (j0 + jt + n);
        float2 mk = *(const float2*)&mask[((b * 512 + y) << 9) + xc];
        #pragma unroll
        for (int reg = 0; reg < 4; ++reg) {     // D: row(och) = 16*wid+4q+reg, col(pix) = lane&15
          int oc = 16 * wid + 4 * q + reg;
          float h0 = hi0[reg] + hb4[reg], l0 = lo0[reg] + lb4[reg];
          float h1 = hi1[reg] + hb4[reg], l1 = lo1[reg] + lb4[reg];
          f32x2 o;
          o.x = l0 + mk.x * (h0 - l0);
          o.y = l1 + mk.y * (h1 - l1);
          __builtin_nontemporal_store(o, (f32x2*)&out[((size_t)(b * 64 + oc) << 18) + ((size_t)y << 9) + xc]);
        }
      };

      const f32x4 z4 = {0.f, 0.f, 0.f, 0.f};
      f32x4 h0, l0, h1, l1;
      // ---- y row py=0 ----
      // phase (0,0): w(1,1)@(i,j)
      h0 = z4; l0 = z4;
      MF(h0, bh[4][0], ah[0][0][0]); MF(h0, bh[4][1], ah[0][0][1]);
      MF(l0, bl[0], lf0);
      // phase (0,1): w(1,0)@(i,j+1) + w(1,2)@(i,j)
      h1 = z4; l1 = z4;
      MF(h1, bh[3][0], ah[0][1][0]); MF(h1, bh[3][1], ah[0][1][1]);
      MF(h1, bh[5][0], ah[0][0][0]); MF(h1, bh[5][1], ah[0][0][1]);
      MF(l1, bl[1], lf1);
      epi2(h0, l0, h1, l1, 0);
      // ---- y row py=1 ----
      // phase (1,0): w(0,1)@(i+1,j) + w(2,1)@(i,j)
      h0 = z4; l0 = z4;
      MF(h0, bh[1][0], ah[1][0][0]); MF(h0, bh[1][1], ah[1][0][1]);
      MF(h0, bh[7][0], ah[0][0][0]); MF(h0, bh[7][1], ah[0][0][1]);
      MF(l0, bl[2], lf2);
      // phase (1,1): w(0,0)@(i+1,j+1) + w(0,2)@(i+1,j) + w(2,0)@(i,j+1) + w(2,2)@(i,j)
      h1 = z4; l1 = z4;
      MF(h1, bh[0][0], ah[1][1][0]); MF(h1, bh[0][1], ah[1][1][1]);
      MF(h1, bh[2][0], ah[1][0][0]); MF(h1, bh[2][1], ah[1][0][1]);
      MF(h1, bh[6][0], ah[0][1][0]); MF(h1, bh[6][1], ah[0][1][1]);
      MF(h1, bh[8][0], ah[0][0][0]); MF(h1, bh[8][1], ah[0][0][1]);
      MF(l1, bl[3], lf3); MF(l1, bl[4], lf1);
      epi2(h0, l0, h1, l1, 1);
    }
  }
}

extern "C" void kernel_launch(void* const* d_in, const int* in_sizes, int n_in,
                              void* d_out, int out_size, void* d_ws, size_t ws_size,
                              hipStream_t stream)
{
  const float* x    = (const float*)d_in[0];
  const float* mask = (const float*)d_in[1];
  // d_in[2] = inv_mask, unused (mask is exactly 0.0/1.0)
  const float* hw   = (const float*)d_in[3];
  const float* hb   = (const float*)d_in[4];
  const float* l1w  = (const float*)d_in[5];
  const float* l1b  = (const float*)d_in[6];
  const float* l2w  = (const float*)d_in[7];
  const float* l2b  = (const float*)d_in[8];
  float* out = (float*)d_out;
  u16* ws  = (u16*)d_ws;
  u16* whi = ws;                 // 36864 elems
  u16* wlo = whi + 36864;        // 10240 elems
  u16* w1f = whi + 47104;        // 1024 elems

  wprep<<<188, 256, 0, stream>>>(hw, l2w, l1w, whi, wlo, w1f);
  tconv_main<<<dim3(4, 64, 4), 256, 0, stream>>>(x, whi, wlo, w1f, mask, hb, l2b, l1b, out);
}